// Round 1
// baseline (445.965 us; speedup 1.0000x reference)
//
#include <hip/hip_runtime.h>
#include <stdint.h>

// SO2MLP: out = so2_linear(rot_act(so2_linear(x,W1)), W2)
// Restructured: Xr = rotate(x); A = leaky(Xr@W1^T); G = A@W2^T; out = rotate_back(G).
// K2 is a fused per-degree dual-GEMM (bf16 MFMA, fp32 accum); rotations live in
// the pointwise pre/post kernels.

#define LMAX 6
#define NN 20000
#define RIN 256
#define RHID 512
#define ROUT 256
#define MROWS (2*NN)         // 40000 (n,c) rows per degree
#define MTILE 128
#define NMT 313              // ceil(40000/128)
#define MPAD (NMT*MTILE)     // 40064

typedef __attribute__((ext_vector_type(8))) short short8;
typedef __attribute__((ext_vector_type(4))) float f32x4;

__device__ __forceinline__ uint16_t f2bf(float f) {
  uint32_t x = __builtin_bit_cast(uint32_t, f);
  x += 0x7fffu + ((x >> 16) & 1u);   // round-to-nearest-even
  return (uint16_t)(x >> 16);
}
__device__ __forceinline__ float bf2f(uint16_t u) {
  return __builtin_bit_cast(float, ((uint32_t)u) << 16);
}

__device__ __forceinline__ f32x4 mfma16(short8 a, short8 b, f32x4 c) {
  return __builtin_amdgcn_mfma_f32_16x16x32_bf16(a, b, c, 0, 0, 0);
}

// ---------------------------------------------------------------------------
// K1a: weights fp32 -> bf16 in B-fragment-linear layout.
// For mfma_f32_16x16x32_bf16, B operand: lane holds col = lane&15,
// k = 8*(lane>>4) + j (j=0..7 contiguous). We store each (ofrag,kstep)
// fragment as 64 lanes x 16B contiguous => coalesced 1KB wave loads in K2.
// ---------------------------------------------------------------------------
__global__ void prep_weights(const float* __restrict__ W1, const float* __restrict__ W2,
                             uint16_t* __restrict__ w1f, uint16_t* __restrict__ w2f) {
  int idx = blockIdx.x * 256 + threadIdx.x;
  if (idx >= LMAX * RHID * RIN) return;
  {
    // W1[l][o][i], K=RIN=256 -> 8 ksteps
    int l = idx / (RHID * RIN);
    int rem = idx - l * (RHID * RIN);
    int o = rem >> 8;
    int i = rem & 255;
    int lane = ((i >> 3) & 3) * 16 + (o & 15);
    size_t dst = (size_t)l * (RHID * RIN) +
                 ((((size_t)(o >> 4) * 8 + (i >> 5)) * 64 + lane) * 8 + (i & 7));
    w1f[dst] = f2bf(W1[idx]);
  }
  {
    // W2[l][o][j], K=RHID=512 -> 16 ksteps
    int l = idx / (ROUT * RHID);
    int rem = idx - l * (ROUT * RHID);
    int o = rem >> 9;
    int j = rem & 511;
    int lane = ((j >> 3) & 3) * 16 + (o & 15);
    size_t dst = (size_t)l * (ROUT * RHID) +
                 ((((size_t)(o >> 4) * 16 + (j >> 5)) * 64 + lane) * 8 + (j & 7));
    w2f[dst] = f2bf(W2[idx]);
  }
}

// ---------------------------------------------------------------------------
// K1b: input rotation + bf16 cast + degree-planar relayout.
// Xr[l][m=2n+c][i] = sum_m' x[n,i,l,m'] * rot[n,l,m',c]
// ---------------------------------------------------------------------------
__global__ void prep_x(const float* __restrict__ x, const float* __restrict__ rot,
                       uint16_t* __restrict__ xr) {
  int t = blockIdx.x * 256 + threadIdx.x;   // t = n*256 + i
  if (t >= NN * RIN) return;
  int n = t >> 8, i = t & 255;
  const float4* xp = (const float4*)(x + (size_t)t * 12);
  float4 v0 = xp[0], v1 = xp[1], v2 = xp[2];
  float xv[12] = {v0.x, v0.y, v0.z, v0.w, v1.x, v1.y, v1.z, v1.w, v2.x, v2.y, v2.z, v2.w};
  const float* rp = rot + (size_t)n * 24;   // rot[n][l][m][c]
#pragma unroll
  for (int l = 0; l < LMAX; ++l) {
    float c0 = xv[2 * l], c1 = xv[2 * l + 1];
    float r00 = rp[4 * l + 0], r01 = rp[4 * l + 1];
    float r10 = rp[4 * l + 2], r11 = rp[4 * l + 3];
    float a0 = c0 * r00 + c1 * r10;   // c=0
    float a1 = c0 * r01 + c1 * r11;   // c=1
    size_t base = (size_t)l * MPAD * RIN + (size_t)(2 * n) * RIN + i;
    xr[base] = f2bf(a0);
    xr[base + RIN] = f2bf(a1);
  }
}

// ---------------------------------------------------------------------------
// K2: fused dual GEMM per (degree, 128-row tile). 512 threads = 8 waves,
// wave grid 2(M) x 4(N). LDS: Xs 64KB (A operand, XOR-swizzled) +
// A2 32KB (leaky(H) chunk). Hidden dim streamed in 4 chunks of 128 so the
// 128x512 intermediate never exists in full.
// ---------------------------------------------------------------------------
__global__ __launch_bounds__(512, 2) void so2_gemm(
    const uint16_t* __restrict__ xr,
    const uint16_t* __restrict__ w1f,
    const uint16_t* __restrict__ w2f,
    uint16_t* __restrict__ g) {
  __shared__ alignas(16) uint8_t XsB[MTILE * RIN * 2];   // 65536 B
  __shared__ alignas(16) uint8_t A2B[MTILE * 128 * 2];   // 32768 B

  const int l = blockIdx.y;
  const int m0 = blockIdx.x * MTILE;
  const int tid = threadIdx.x;
  const int lane = tid & 63;
  const int wid = tid >> 6;
  const int wm = wid & 1;    // 64-row group
  const int wn = wid >> 1;   // 0..3 col group
  const int l15 = lane & 15;
  const int l4 = lane >> 4;

  // ---- stage Xr tile (128 rows x 512 B) into swizzled LDS ----
  const char* xsrc = (const char*)(xr + (size_t)l * MPAD * RIN + (size_t)m0 * RIN);
#pragma unroll
  for (int it = 0; it < 8; ++it) {
    int off = it * 8192 + tid * 16;
    int row = off >> 9;
    int colb = off & 511;
    short8 v = *(const short8*)(xsrc + off);
    *(short8*)(XsB + row * 512 + (colb ^ ((row & 7) << 4))) = v;
  }
  __syncthreads();

  const uint16_t* w1p = w1f + (size_t)l * RHID * RIN;
  const uint16_t* w2p = w2f + (size_t)l * ROUT * RHID;

  f32x4 acc2[4][4];
#pragma unroll
  for (int a = 0; a < 4; ++a)
#pragma unroll
    for (int b = 0; b < 4; ++b)
      acc2[a][b] = (f32x4){0.f, 0.f, 0.f, 0.f};

#pragma unroll 1
  for (int oc = 0; oc < 4; ++oc) {
    // ---- GEMM1 chunk: H[:, oc*128 .. +128) ----
    f32x4 acc1[4][2];
#pragma unroll
    for (int a = 0; a < 4; ++a)
#pragma unroll
      for (int b = 0; b < 2; ++b)
        acc1[a][b] = (f32x4){0.f, 0.f, 0.f, 0.f};

#pragma unroll
    for (int ks = 0; ks < 8; ++ks) {
      short8 af[4];
#pragma unroll
      for (int rf = 0; rf < 4; ++rf) {
        int row = wm * 64 + rf * 16 + l15;
        int colb = ks * 64 + l4 * 16;
        af[rf] = *(const short8*)(XsB + row * 512 + (colb ^ ((row & 7) << 4)));
      }
      short8 bfr[2];
#pragma unroll
      for (int fc = 0; fc < 2; ++fc) {
        int ofrag = oc * 8 + wn * 2 + fc;
        bfr[fc] = *(const short8*)(w1p + (((size_t)(ofrag * 8 + ks)) * 64 + lane) * 8);
      }
#pragma unroll
      for (int rf = 0; rf < 4; ++rf)
#pragma unroll
        for (int fc = 0; fc < 2; ++fc)
          acc1[rf][fc] = mfma16(af[rf], bfr[fc], acc1[rf][fc]);
    }

    __syncthreads();   // previous chunk's GEMM2 reads of A2B are done
    // ---- leaky relu + bf16 -> A2B (swizzled) ----
#pragma unroll
    for (int rf = 0; rf < 4; ++rf)
#pragma unroll
      for (int fc = 0; fc < 2; ++fc)
#pragma unroll
        for (int r = 0; r < 4; ++r) {
          int row = wm * 64 + rf * 16 + l4 * 4 + r;   // D: row=(lane>>4)*4+reg
          int col = wn * 32 + fc * 16 + l15;          // D: col=lane&15
          float v = acc1[rf][fc][r];
          v = v >= 0.f ? v : 0.01f * v;
          *(uint16_t*)(A2B + row * 256 + ((col * 2) ^ ((row & 7) << 4))) = f2bf(v);
        }
    __syncthreads();

    // ---- GEMM2 partial accumulation over this K-chunk of 128 ----
#pragma unroll
    for (int ks2 = 0; ks2 < 4; ++ks2) {
      short8 a2[4];
#pragma unroll
      for (int rf = 0; rf < 4; ++rf) {
        int row = wm * 64 + rf * 16 + l15;
        int colb = ks2 * 64 + l4 * 16;
        a2[rf] = *(const short8*)(A2B + row * 256 + (colb ^ ((row & 7) << 4)));
      }
      short8 b2[4];
#pragma unroll
      for (int fc2 = 0; fc2 < 4; ++fc2) {
        int ofrag2 = wn * 4 + fc2;
        int kstep = oc * 4 + ks2;
        b2[fc2] = *(const short8*)(w2p + (((size_t)(ofrag2 * 16 + kstep)) * 64 + lane) * 8);
      }
#pragma unroll
      for (int rf = 0; rf < 4; ++rf)
#pragma unroll
        for (int fc2 = 0; fc2 < 4; ++fc2)
          acc2[rf][fc2] = mfma16(a2[rf], b2[fc2], acc2[rf][fc2]);
    }
  }

  // ---- epilogue: G tile -> bf16 via LDS (Xs dead, reuse) -> coalesced store
#pragma unroll
  for (int rf = 0; rf < 4; ++rf)
#pragma unroll
    for (int fc2 = 0; fc2 < 4; ++fc2)
#pragma unroll
      for (int r = 0; r < 4; ++r) {
        int row = wm * 64 + rf * 16 + l4 * 4 + r;
        int col = wn * 64 + fc2 * 16 + l15;
        *(uint16_t*)(XsB + row * 512 + ((col * 2) ^ ((row & 7) << 4))) = f2bf(acc2[rf][fc2][r]);
      }
  __syncthreads();

  char* gdst = (char*)(g + (size_t)l * MPAD * ROUT + (size_t)m0 * ROUT);
#pragma unroll
  for (int it = 0; it < 8; ++it) {
    int off = it * 8192 + tid * 16;
    int row = off >> 9;
    int colb = off & 511;
    short8 v = *(const short8*)(XsB + row * 512 + (colb ^ ((row & 7) << 4)));
    *(short8*)(gdst + off) = v;
  }
}

// ---------------------------------------------------------------------------
// K3: output rotation + fp32 store, fully coalesced (48 B per thread).
// out[n,o,l,m] = sum_c rot[n,l,m,c] * G[l][2n+c][o]
// ---------------------------------------------------------------------------
__global__ void post_out(const uint16_t* __restrict__ g, const float* __restrict__ rot,
                         float* __restrict__ out) {
  int n = blockIdx.x;
  int o = threadIdx.x;
  const float* rp = rot + (size_t)n * 24;
  float res[12];
#pragma unroll
  for (int l = 0; l < LMAX; ++l) {
    size_t base = (size_t)l * MPAD * ROUT + (size_t)(2 * n) * ROUT + o;
    float g0 = bf2f(g[base]);
    float g1 = bf2f(g[base + ROUT]);
    res[2 * l]     = rp[4 * l + 0] * g0 + rp[4 * l + 1] * g1;   // m=0
    res[2 * l + 1] = rp[4 * l + 2] * g0 + rp[4 * l + 3] * g1;   // m=1
  }
  float4* op = (float4*)(out + (size_t)(n * 256 + o) * 12);
  op[0] = make_float4(res[0], res[1], res[2], res[3]);
  op[1] = make_float4(res[4], res[5], res[6], res[7]);
  op[2] = make_float4(res[8], res[9], res[10], res[11]);
}

// ---------------------------------------------------------------------------
extern "C" void kernel_launch(void* const* d_in, const int* in_sizes, int n_in,
                              void* d_out, int out_size, void* d_ws, size_t ws_size,
                              hipStream_t stream) {
  (void)in_sizes; (void)n_in; (void)out_size;
  const float* x   = (const float*)d_in[0];
  const float* rot = (const float*)d_in[1];
  const float* W1  = (const float*)d_in[2];
  const float* W2  = (const float*)d_in[3];
  float* out = (float*)d_out;

  // Scratch plan:
  //   d_out (245.76 MB, overwritten by K3 at the end) doubles as scratch:
  //     [0, 123.08 MB)          Xr: 6 planes of [MPAD][RIN] bf16
  //     [123.08, 124.65 MB)     W1 bf16 fragment-linear
  //     [124.65, 126.22 MB)     W2 bf16 fragment-linear
  //   d_ws: G: 6 planes of [MPAD][ROUT] bf16 = 123,076,608 B
  const size_t xr_elems = (size_t)LMAX * MPAD * RIN;        // 61,538,304
  const size_t w_elems  = (size_t)LMAX * RHID * RIN;        // 786,432 (same for W2)
  if (ws_size < (size_t)LMAX * MPAD * ROUT * 2) return;     // need 123,076,608 B

  uint16_t* xr  = (uint16_t*)d_out;
  uint16_t* w1f = xr + xr_elems;
  uint16_t* w2f = w1f + w_elems;
  uint16_t* g   = (uint16_t*)d_ws;

  prep_weights<<<3072, 256, 0, stream>>>(W1, W2, w1f, w2f);
  prep_x<<<20000, 256, 0, stream>>>(x, rot, xr);
  dim3 gg(NMT, LMAX);
  so2_gemm<<<gg, 512, 0, stream>>>(xr, w1f, w2f, g);
  post_out<<<20000, 256, 0, stream>>>(g, rot, out);
}

// Round 2
// 309.625 us; speedup vs baseline: 1.4403x; 1.4403x over previous
//
#include <hip/hip_runtime.h>
#include <stdint.h>

// SO2MLP: out = so2_linear(rot_act(so2_linear(x,W1)), W2)
// Restructured: Xr = rotate(x); A = leaky(Xr@W1^T); G = A@W2^T; out = rotate_back(G).
// K2 is a fused per-degree dual-GEMM (bf16 MFMA, fp32 accum); rotations live in
// the pointwise pre/post kernels.
//
// R2 changes vs R1: MTILE 128->64 (LDS 96KB->49KB, 1->2 blocks/CU), per-wave
// disjoint weight fragments (no wm-duplicated W reads), A2B pad-stride 272B
// (bank conflicts), epilogue staging stride 528B.

#define LMAX 6
#define NN 20000
#define RIN 256
#define RHID 512
#define ROUT 256
#define MTILE 64
#define NMT 626              // 40064/64
#define MPAD (NMT*MTILE)     // 40064

#define A2_STRIDE 272        // 64x272 = 17408 B, bank-start 4*row%32
#define GE_STRIDE 528        // epilogue staging stride

typedef __attribute__((ext_vector_type(8))) short short8;
typedef __attribute__((ext_vector_type(4))) float f32x4;

__device__ __forceinline__ uint16_t f2bf(float f) {
  uint32_t x = __builtin_bit_cast(uint32_t, f);
  x += 0x7fffu + ((x >> 16) & 1u);   // round-to-nearest-even
  return (uint16_t)(x >> 16);
}
__device__ __forceinline__ float bf2f(uint16_t u) {
  return __builtin_bit_cast(float, ((uint32_t)u) << 16);
}

__device__ __forceinline__ f32x4 mfma16(short8 a, short8 b, f32x4 c) {
  return __builtin_amdgcn_mfma_f32_16x16x32_bf16(a, b, c, 0, 0, 0);
}

// ---------------------------------------------------------------------------
// K1a: weights fp32 -> bf16 in fragment-linear layout (verified in R1).
// Fragment: lane holds (row-or-col)=lane&15, k = 8*(lane>>4)+j, j=0..7
// contiguous; each (ofrag,kstep) fragment stored as 64 lanes x 16B => 1KB
// contiguous, coalesced wave loads in K2.
// ---------------------------------------------------------------------------
__global__ void prep_weights(const float* __restrict__ W1, const float* __restrict__ W2,
                             uint16_t* __restrict__ w1f, uint16_t* __restrict__ w2f) {
  int idx = blockIdx.x * 256 + threadIdx.x;
  if (idx >= LMAX * RHID * RIN) return;
  {
    // W1[l][o][i], K=RIN=256 -> 8 ksteps
    int l = idx / (RHID * RIN);
    int rem = idx - l * (RHID * RIN);
    int o = rem >> 8;
    int i = rem & 255;
    int lane = ((i >> 3) & 3) * 16 + (o & 15);
    size_t dst = (size_t)l * (RHID * RIN) +
                 ((((size_t)(o >> 4) * 8 + (i >> 5)) * 64 + lane) * 8 + (i & 7));
    w1f[dst] = f2bf(W1[idx]);
  }
  {
    // W2[l][o][j], K=RHID=512 -> 16 ksteps
    int l = idx / (ROUT * RHID);
    int rem = idx - l * (ROUT * RHID);
    int o = rem >> 9;
    int j = rem & 511;
    int lane = ((j >> 3) & 3) * 16 + (o & 15);
    size_t dst = (size_t)l * (ROUT * RHID) +
                 ((((size_t)(o >> 4) * 16 + (j >> 5)) * 64 + lane) * 8 + (j & 7));
    w2f[dst] = f2bf(W2[idx]);
  }
}

// ---------------------------------------------------------------------------
// K1b: input rotation + bf16 cast + degree-planar relayout.
// Xr[l][m=2n+c][i] = sum_m' x[n,i,l,m'] * rot[n,l,m',c]
// ---------------------------------------------------------------------------
__global__ void prep_x(const float* __restrict__ x, const float* __restrict__ rot,
                       uint16_t* __restrict__ xr) {
  int t = blockIdx.x * 256 + threadIdx.x;   // t = n*256 + i
  if (t >= NN * RIN) return;
  int n = t >> 8, i = t & 255;
  const float4* xp = (const float4*)(x + (size_t)t * 12);
  float4 v0 = xp[0], v1 = xp[1], v2 = xp[2];
  float xv[12] = {v0.x, v0.y, v0.z, v0.w, v1.x, v1.y, v1.z, v1.w, v2.x, v2.y, v2.z, v2.w};
  const float* rp = rot + (size_t)n * 24;   // rot[n][l][m][c]
#pragma unroll
  for (int l = 0; l < LMAX; ++l) {
    float c0 = xv[2 * l], c1 = xv[2 * l + 1];
    float r00 = rp[4 * l + 0], r01 = rp[4 * l + 1];
    float r10 = rp[4 * l + 2], r11 = rp[4 * l + 3];
    float a0 = c0 * r00 + c1 * r10;   // c=0
    float a1 = c0 * r01 + c1 * r11;   // c=1
    size_t base = (size_t)l * MPAD * RIN + (size_t)(2 * n) * RIN + i;
    xr[base] = f2bf(a0);
    xr[base + RIN] = f2bf(a1);
  }
}

// ---------------------------------------------------------------------------
// K2: fused dual GEMM per (degree, 64-row tile). 512 threads = 8 waves.
// GEMM1: wave w owns hidden frag (oc*8+w), all 4 m-frags  (disjoint W1 reads)
// GEMM2: wave w owns out frags {2w, 2w+1}, all 4 m-frags  (disjoint W2 reads)
// LDS: Xs 32KB (XOR-swizzle) + A2B 17KB (pad-stride)  -> 49KB.
// ---------------------------------------------------------------------------
__global__ __launch_bounds__(512, 4) void so2_gemm(
    const uint16_t* __restrict__ xr,
    const uint16_t* __restrict__ w1f,
    const uint16_t* __restrict__ w2f,
    uint16_t* __restrict__ g) {
  __shared__ alignas(16) uint8_t SH[32768 + MTILE * A2_STRIDE];  // 50176 B
  uint8_t* XsB = SH;                 // [64][512B], XOR-swizzled
  uint8_t* A2B = SH + 32768;         // [64][A2_STRIDE], linear

  const int l = blockIdx.y;
  const int m0 = blockIdx.x * MTILE;
  const int tid = threadIdx.x;
  const int lane = tid & 63;
  const int wid = tid >> 6;
  const int l15 = lane & 15;
  const int l4 = lane >> 4;

  // ---- stage Xr tile (64 rows x 512 B) into swizzled LDS: 4 x 8KB ----
  const char* xsrc = (const char*)(xr + (size_t)l * MPAD * RIN + (size_t)m0 * RIN);
#pragma unroll
  for (int it = 0; it < 4; ++it) {
    int off = it * 8192 + tid * 16;
    int row = off >> 9;
    int colb = off & 511;
    short8 v = *(const short8*)(xsrc + off);
    *(short8*)(XsB + row * 512 + (colb ^ ((row & 7) << 4))) = v;
  }
  __syncthreads();

  const uint16_t* w1p = w1f + (size_t)l * RHID * RIN;
  const uint16_t* w2p = w2f + (size_t)l * ROUT * RHID;

  f32x4 acc2[4][2];
#pragma unroll
  for (int a = 0; a < 4; ++a)
#pragma unroll
    for (int b = 0; b < 2; ++b)
      acc2[a][b] = (f32x4){0.f, 0.f, 0.f, 0.f};

#pragma unroll 1
  for (int oc = 0; oc < 4; ++oc) {
    // ---- GEMM1: hidden frag (oc*8 + wid), 4 m-frags, K=256 ----
    f32x4 acc1[4];
#pragma unroll
    for (int a = 0; a < 4; ++a) acc1[a] = (f32x4){0.f, 0.f, 0.f, 0.f};

    const uint16_t* w1c = w1p + (((size_t)(oc * 8 + wid) * 8) * 64) * 8;
#pragma unroll
    for (int ks = 0; ks < 8; ++ks) {
      short8 bfr = *(const short8*)(w1c + ((size_t)ks * 64 + lane) * 8);
#pragma unroll
      for (int mf = 0; mf < 4; ++mf) {
        int row = mf * 16 + l15;
        int colb = ks * 64 + l4 * 16;
        short8 af = *(const short8*)(XsB + row * 512 + (colb ^ ((row & 7) << 4)));
        acc1[mf] = mfma16(af, bfr, acc1[mf]);
      }
    }

    __syncthreads();   // previous chunk's GEMM2 reads of A2B are done
    // ---- leaky relu + bf16 -> A2B ----
    // D layout: row_in_frag = l4*4+r, col_in_frag = l15
#pragma unroll
    for (int mf = 0; mf < 4; ++mf)
#pragma unroll
      for (int r = 0; r < 4; ++r) {
        int row = mf * 16 + l4 * 4 + r;
        float v = acc1[mf][r];
        v = v >= 0.f ? v : 0.01f * v;
        *(uint16_t*)(A2B + row * A2_STRIDE + (wid * 16 + l15) * 2) = f2bf(v);
      }
    __syncthreads();

    // ---- GEMM2 partial accumulation over this 128-hidden chunk ----
#pragma unroll
    for (int ks2 = 0; ks2 < 4; ++ks2) {
      short8 a2[4];
#pragma unroll
      for (int mf = 0; mf < 4; ++mf)
        a2[mf] = *(const short8*)(A2B + (mf * 16 + l15) * A2_STRIDE + ks2 * 64 + l4 * 16);
      short8 b2[2];
#pragma unroll
      for (int fc2 = 0; fc2 < 2; ++fc2) {
        int ofrag2 = wid * 2 + fc2;
        int kstep = oc * 4 + ks2;
        b2[fc2] = *(const short8*)(w2p + (((size_t)(ofrag2 * 16 + kstep)) * 64 + lane) * 8);
      }
#pragma unroll
      for (int mf = 0; mf < 4; ++mf)
#pragma unroll
        for (int fc2 = 0; fc2 < 2; ++fc2)
          acc2[mf][fc2] = mfma16(a2[mf], b2[fc2], acc2[mf][fc2]);
    }
  }

  // ---- epilogue: G tile -> bf16 via LDS (stride 528) -> coalesced store ----
  __syncthreads();   // last GEMM2 A2B reads done; SH reused below
#pragma unroll
  for (int mf = 0; mf < 4; ++mf)
#pragma unroll
    for (int fc2 = 0; fc2 < 2; ++fc2)
#pragma unroll
      for (int r = 0; r < 4; ++r) {
        int row = mf * 16 + l4 * 4 + r;
        int col = wid * 32 + fc2 * 16 + l15;
        *(uint16_t*)(SH + row * GE_STRIDE + col * 2) = f2bf(acc2[mf][fc2][r]);
      }
  __syncthreads();

  char* gdst = (char*)(g + (size_t)l * MPAD * ROUT + (size_t)m0 * ROUT);
#pragma unroll
  for (int it = 0; it < 4; ++it) {
    int off = it * 8192 + tid * 16;
    int row = off >> 9;
    int colb = off & 511;
    short8 v = *(const short8*)(SH + row * GE_STRIDE + colb);
    *(short8*)(gdst + off) = v;
  }
}

// ---------------------------------------------------------------------------
// K3: output rotation + fp32 store, fully coalesced (48 B per thread).
// out[n,o,l,m] = sum_c rot[n,l,m,c] * G[l][2n+c][o]
// ---------------------------------------------------------------------------
__global__ void post_out(const uint16_t* __restrict__ g, const float* __restrict__ rot,
                         float* __restrict__ out) {
  int n = blockIdx.x;
  int o = threadIdx.x;
  const float* rp = rot + (size_t)n * 24;
  float res[12];
#pragma unroll
  for (int l = 0; l < LMAX; ++l) {
    size_t base = (size_t)l * MPAD * ROUT + (size_t)(2 * n) * ROUT + o;
    float g0 = bf2f(g[base]);
    float g1 = bf2f(g[base + ROUT]);
    res[2 * l]     = rp[4 * l + 0] * g0 + rp[4 * l + 1] * g1;   // m=0
    res[2 * l + 1] = rp[4 * l + 2] * g0 + rp[4 * l + 3] * g1;   // m=1
  }
  float4* op = (float4*)(out + (size_t)(n * 256 + o) * 12);
  op[0] = make_float4(res[0], res[1], res[2], res[3]);
  op[1] = make_float4(res[4], res[5], res[6], res[7]);
  op[2] = make_float4(res[8], res[9], res[10], res[11]);
}

// ---------------------------------------------------------------------------
extern "C" void kernel_launch(void* const* d_in, const int* in_sizes, int n_in,
                              void* d_out, int out_size, void* d_ws, size_t ws_size,
                              hipStream_t stream) {
  (void)in_sizes; (void)n_in; (void)out_size;
  const float* x   = (const float*)d_in[0];
  const float* rot = (const float*)d_in[1];
  const float* W1  = (const float*)d_in[2];
  const float* W2  = (const float*)d_in[3];
  float* out = (float*)d_out;

  // Scratch plan:
  //   d_out (245.76 MB, overwritten by K3 at the end) doubles as scratch:
  //     [0, 123.08 MB)          Xr: 6 planes of [MPAD][RIN] bf16
  //     [123.08, 124.65 MB)     W1 bf16 fragment-linear
  //     [124.65, 126.22 MB)     W2 bf16 fragment-linear
  //   d_ws: G: 6 planes of [MPAD][ROUT] bf16 = 123,076,608 B
  const size_t xr_elems = (size_t)LMAX * MPAD * RIN;        // 61,538,304
  const size_t w_elems  = (size_t)LMAX * RHID * RIN;        // 786,432 (same for W2)
  if (ws_size < (size_t)LMAX * MPAD * ROUT * 2) return;     // need 123,076,608 B

  uint16_t* xr  = (uint16_t*)d_out;
  uint16_t* w1f = xr + xr_elems;
  uint16_t* w2f = w1f + w_elems;
  uint16_t* g   = (uint16_t*)d_ws;

  prep_weights<<<3072, 256, 0, stream>>>(W1, W2, w1f, w2f);
  prep_x<<<20000, 256, 0, stream>>>(x, rot, xr);
  dim3 gg(NMT, LMAX);
  so2_gemm<<<gg, 512, 0, stream>>>(xr, w1f, w2f, g);
  post_out<<<20000, 256, 0, stream>>>(g, rot, out);
}